// Round 14
// baseline (201.305 us; speedup 1.0000x reference)
//
#include <hip/hip_runtime.h>
#include <hip/hip_bf16.h>

#define BATCH 4
#define SEQ 4096
#define DMODEL 2048
#define HD 128
#define BS (BATCH*SEQ)

typedef __attribute__((ext_vector_type(8))) short short8;
typedef __attribute__((ext_vector_type(4))) float f32x4;
typedef __attribute__((ext_vector_type(4))) float float4v;
typedef unsigned short u16;
typedef unsigned int u32;

#define LOG2E 1.4426950408889634f
#define SCALE 0.08838834764831845f /* 1/sqrt(128) */

__device__ __forceinline__ u16 f2bf(float f){
  u32 u = __builtin_bit_cast(u32, f);
  u32 r = (u + 0x7FFFu + ((u >> 16) & 1u)) >> 16;
  return (u16)r;
}
__device__ __forceinline__ float bf2f(u16 b){
  u32 u = ((u32)b) << 16;
  return __builtin_bit_cast(float, u);
}

__device__ __forceinline__ void gload16(const void* gptr, void* lptr){
  __builtin_amdgcn_global_load_lds((const __attribute__((address_space(1))) void*)gptr,
                                   (__attribute__((address_space(3))) void*)lptr, 16, 0, 0);
}

// ---------------- trig table + weight convert, merged ----------------
__global__ __launch_bounds__(256) void k_prep(float2* __restrict__ tab,
                                              const float* __restrict__ wq, const float* __restrict__ wk,
                                              const float* __restrict__ wv, u16* __restrict__ wb){
  int bidx = blockIdx.x;
  if (bidx < 1024){
    int i = bidx*256 + threadIdx.x;            // 4096*64 total
    int s = i >> 6, j = i & 63;
    float invf = (float)pow(10000.0, -(double)j/64.0);
    float ang  = (float)s * invf;              // mimic fp32 reference rounding of the angle
    double a = (double)ang;
    tab[i] = make_float2((float)cos(a), (float)sin(a));
  } else {
    int i = (bidx - 1024)*256 + threadIdx.x;   // 3*262144 total
    int m = i >> 18; int r = i & 262143;
    const float* s = (m==0) ? wq : ((m==1) ? wk : wv);
    wb[i] = f2bf(s[r]);
  }
}

// ---------------- QKV projection GEMM: barrier-free register streaming ----------------
// 1536 blocks x 64 threads = 1 wave each, tile 32 rows x 128 cols (ng = Q/K/V).
// NO LDS, NO barriers, NO manual waitcnt: A (fp32 x, cvt in-reg) and W (bf16, L2-resident)
// fragments loaded directly from global; compiler + 6 waves/CU MLP hide latency.
// bid%3 = ng so the 3 blocks sharing an x-tile are adjacent (L2/L3 reuse).
__global__ __launch_bounds__(64) void k_gemm(
    const float* __restrict__ x, const u16* __restrict__ wb, const float2* __restrict__ tab,
    u16* __restrict__ qb, u16* __restrict__ kb, u16* __restrict__ vt)
{
  const int lane = threadIdx.x & 63, lr = lane & 15, lg = lane >> 4;
  const int bid = blockIdx.x;
  const int wsel = bid % 3;
  const int mg = bid / 3;                      // 0..511
  const size_t M0 = (size_t)mg * 32;
  const u16* Wm = wb + (size_t)wsel * (HD*DMODEL);

  const float* ax0 = x + (M0 + lr)*DMODEL + lg*8;
  const float* ax1 = x + (M0 + 16 + lr)*DMODEL + lg*8;
  const u16* wp[8];
  #pragma unroll
  for (int nf=0; nf<8; nf++) wp[nf] = Wm + (size_t)(nf*16 + lr)*DMODEL + lg*8;

  f32x4 acc[2][8];
  #pragma unroll
  for (int i=0;i<2;i++)
    #pragma unroll
    for (int j=0;j<8;j++) acc[i][j] = f32x4{0.f,0.f,0.f,0.f};

  for (int t=0; t<32; t++){
    const int k0 = t*64;
    short8 af[2][2];
    #pragma unroll
    for (int rf=0; rf<2; rf++){
      const float* ap = (rf == 0) ? ax0 : ax1;
      #pragma unroll
      for (int ks=0; ks<2; ks++){
        float4v a0 = *(const float4v*)(ap + k0 + ks*32);
        float4v a1 = *(const float4v*)(ap + k0 + ks*32 + 4);
        short8 o;
        o[0]=(short)f2bf(a0[0]); o[1]=(short)f2bf(a0[1]); o[2]=(short)f2bf(a0[2]); o[3]=(short)f2bf(a0[3]);
        o[4]=(short)f2bf(a1[0]); o[5]=(short)f2bf(a1[1]); o[6]=(short)f2bf(a1[2]); o[7]=(short)f2bf(a1[3]);
        af[rf][ks] = o;
      }
    }
    #pragma unroll
    for (int nf=0; nf<8; nf++){
      short8 w0 = *(const short8*)(wp[nf] + k0);
      short8 w1 = *(const short8*)(wp[nf] + k0 + 32);
      #pragma unroll
      for (int rf=0; rf<2; rf++){
        acc[rf][nf] = __builtin_amdgcn_mfma_f32_16x16x32_bf16(af[rf][0], w0, acc[rf][nf], 0,0,0);
        acc[rf][nf] = __builtin_amdgcn_mfma_f32_16x16x32_bf16(af[rf][1], w1, acc[rf][nf], 0,0,0);
      }
    }
  }

  // epilogue: RoPE (cols j / j+64 are cf / cf+4) -> qb/kb; V transposed -> vt
  if (wsel < 2){
    u16* dst = (wsel == 0) ? qb : kb;
    #pragma unroll
    for (int rf=0; rf<2; rf++){
      #pragma unroll
      for (int reg=0; reg<4; reg++){
        size_t grow = M0 + rf*16 + lg*4 + reg;
        int spos = (int)(grow & (SEQ-1));
        #pragma unroll
        for (int cf=0; cf<4; cf++){
          int j = cf*16 + lr;                 // 0..63
          float2 cs = tab[spos*64 + j];
          float lo = acc[rf][cf][reg];
          float hi = acc[rf][cf+4][reg];
          dst[grow*HD + j]      = f2bf(lo*cs.x - hi*cs.y);
          dst[grow*HD + j + 64] = f2bf(hi*cs.x + lo*cs.y);
        }
      }
    }
  } else {
    #pragma unroll
    for (int rf=0; rf<2; rf++)
      #pragma unroll
      for (int reg=0; reg<4; reg++){
        size_t grow = M0 + rf*16 + lg*4 + reg;
        size_t b = grow >> 12;
        size_t spos = grow & (SEQ-1);
        #pragma unroll
        for (int cf=0; cf<8; cf++){
          int col = cf*16 + lr;
          vt[(b*HD + col)*SEQ + spos] = f2bf(acc[rf][cf][reg]);
        }
      }
  }
}

// ---------------- causal flash attention, 4-way KV split (flash-decoding) ----------------
// grid 1024: (batch, 64-row q-tile, kv-split). 4 waves x 16 q-rows share staged lK/lV.
// LDS 40KB -> 4 blocks/CU -> 16 waves/CU. Partials (O bf16, ml fp32) to workspace.
__global__ __launch_bounds__(256) void k_attn(
    const u16* __restrict__ qbuf, const u16* __restrict__ kb, const u16* __restrict__ vt,
    u16* __restrict__ Opart, float2* __restrict__ ml)
{
  __shared__ u16 lK[64*128];    // byte = kv*256 + (cb ^ ((kv&7)<<4))
  __shared__ u16 lV[128*64];    // byte = d*128  + (cb ^ ((d&7)<<4))
  __shared__ u16 lP[4][16*64];  // per-wave, byte = r*128 + (cb ^ ((r&7)<<4))
  const int tid = threadIdx.x;
  const int bid = blockIdx.x;
  const int x = bid & 7, idx = bid >> 3;
  const int b = x >> 1, half = x & 1;
  const int qt = 63 - (idx >> 1);              // heavy tiles first
  const int sp = (idx & 1) + 2*half;           // kv-split 0..3
  const int qbn = b*64 + qt;                   // 0..255
  const int w = tid >> 6, lane = tid & 63, lr = lane & 15, lg = lane >> 4;

  // balanced contiguous partition of tiles [0, qt] into 4 chunks
  const int n = qt + 1, cbase = n >> 2, crem = n & 3;
  const int cnt = cbase + (sp < crem ? 1 : 0);
  const int klo = sp*cbase + (sp < crem ? sp : crem);
  const int khi = klo + cnt;
  const size_t prow0 = ((size_t)qbn*4 + sp)*64;

  if (cnt == 0){                               // empty split: mark and exit (block-uniform)
    if (lr == 0){
      #pragma unroll
      for (int reg=0; reg<4; reg++)
        ml[prow0 + w*16 + lg*4 + reg] = make_float2(-1e30f, 0.f);
    }
    return;
  }

  const size_t qrow = (size_t)b*SEQ + qt*64 + w*16 + lr;
  short8 aq[4];
  #pragma unroll
  for (int ks=0; ks<4; ks++)
    aq[ks] = *(const short8*)(qbuf + qrow*HD + ks*32 + lg*8);

  f32x4 accO[8];
  #pragma unroll
  for (int i=0;i<8;i++) accO[i] = f32x4{0.f,0.f,0.f,0.f};
  float m2[4]   = {-1e30f,-1e30f,-1e30f,-1e30f};
  float lsum[4] = {0.f,0.f,0.f,0.f};

  const int Lb = tid*16;
  const float cfac = SCALE * LOG2E;

  for (int kt = klo; kt < khi; kt++){
    #pragma unroll
    for (int i=0;i<4;i++){
      int L = i*4096 + Lb;
      { int row = L >> 8, cb = L & 255;
        int scb = cb ^ ((row & 7) << 4);
        gload16(kb + ((size_t)b*SEQ + kt*64 + row)*HD + (scb>>1), ((char*)lK) + L); }
      { int row = L >> 7, cb = L & 127;
        int scb = cb ^ ((row & 7) << 4);
        gload16(vt + ((size_t)b*HD + row)*SEQ + kt*64 + (scb>>1), ((char*)lV) + L); }
    }
    __syncthreads();

    // S = Q K^T  (16 q-rows x 64 kv) in log2-domain units
    f32x4 sc[4];
    #pragma unroll
    for (int nf=0; nf<4; nf++){
      sc[nf] = f32x4{0.f,0.f,0.f,0.f};
      #pragma unroll
      for (int ks=0; ks<4; ks++){
        int r = nf*16 + lr;
        int byte = r*256 + ((ks*64 + lg*16) ^ ((r&7)<<4));
        short8 bk = *(const short8*)((const char*)lK + byte);
        sc[nf] = __builtin_amdgcn_mfma_f32_16x16x32_bf16(aq[ks], bk, sc[nf], 0,0,0);
      }
      sc[nf] *= cfac;
    }
    if (kt == qt){                            // diagonal tile: causal mask
      #pragma unroll
      for (int nf=0; nf<4; nf++)
        #pragma unroll
        for (int reg=0; reg<4; reg++){
          int col = nf*16 + lr;
          int row = w*16 + lg*4 + reg;
          if (col > row) sc[nf][reg] = -1e30f;
        }
    }
    float al[4];
    #pragma unroll
    for (int reg=0; reg<4; reg++){
      float v = fmaxf(fmaxf(sc[0][reg], sc[1][reg]), fmaxf(sc[2][reg], sc[3][reg]));
      v = fmaxf(v, __shfl_xor(v, 1));
      v = fmaxf(v, __shfl_xor(v, 2));
      v = fmaxf(v, __shfl_xor(v, 4));
      v = fmaxf(v, __shfl_xor(v, 8));
      float mnew = fmaxf(m2[reg], v);
      al[reg] = exp2f(m2[reg] - mnew);
      m2[reg] = mnew;
    }
    float prs[4] = {0.f,0.f,0.f,0.f};
    #pragma unroll
    for (int nf=0; nf<4; nf++)
      #pragma unroll
      for (int reg=0; reg<4; reg++){
        float p = exp2f(sc[nf][reg] - m2[reg]);
        prs[reg] += p;
        int r = lg*4 + reg;
        int byte = r*128 + ((nf*32 + lr*2) ^ ((r&7)<<4));
        *(u16*)(((char*)lP[w]) + byte) = f2bf(p);
      }
    f32x4 alv = f32x4{al[0], al[1], al[2], al[3]};
    #pragma unroll
    for (int reg=0; reg<4; reg++){
      float v = prs[reg];
      v += __shfl_xor(v, 1);
      v += __shfl_xor(v, 2);
      v += __shfl_xor(v, 4);
      v += __shfl_xor(v, 8);
      lsum[reg] = lsum[reg]*al[reg] + v;
    }
    #pragma unroll
    for (int cf=0; cf<8; cf++) accO[cf] *= alv;

    short8 pa[2];
    #pragma unroll
    for (int ks=0; ks<2; ks++){
      int byte = lr*128 + ((ks*64 + lg*16) ^ ((lr&7)<<4));
      pa[ks] = *(const short8*)(((const char*)lP[w]) + byte);
    }
    #pragma unroll
    for (int cf=0; cf<8; cf++){
      #pragma unroll
      for (int ks=0; ks<2; ks++){
        int d = cf*16 + lr;
        int byte = d*128 + ((ks*64 + lg*16) ^ ((d&7)<<4));
        short8 bv = *(const short8*)(((const char*)lV) + byte);
        accO[cf] = __builtin_amdgcn_mfma_f32_16x16x32_bf16(pa[ks], bv, accO[cf], 0,0,0);
      }
    }
    __syncthreads();
  }

  // partial epilogue: bf16 accO + (m, l) per row
  #pragma unroll
  for (int reg=0; reg<4; reg++){
    size_t pr = prow0 + w*16 + lg*4 + reg;
    #pragma unroll
    for (int cf=0; cf<8; cf++)
      Opart[pr*HD + cf*16 + lr] = f2bf(accO[cf][reg]);
  }
  if (lr == 0){
    #pragma unroll
    for (int reg=0; reg<4; reg++)
      ml[prow0 + w*16 + lg*4 + reg] = make_float2(m2[reg], lsum[reg]);
  }
}

// ---------------- combine partials: out = sum_s O_s * 2^(m_s-M) / L ----------------
// grid 1024: 16 rows/block, 8 cols/thread (bf16 Opart short8 reads).
__global__ __launch_bounds__(256) void k_comb(
    const u16* __restrict__ Opart, const float2* __restrict__ ml, float* __restrict__ out)
{
  const int t = threadIdx.x;
  const int r = blockIdx.x*16 + (t >> 4);      // global row 0..16383
  const int c0 = (t & 15)*8;
  const int qbn = r >> 6, rr = r & 63;
  float m[4], l[4], M = -1e30f;
  #pragma unroll
  for (int s=0; s<4; s++){
    float2 v = ml[((size_t)qbn*4 + s)*64 + rr];
    m[s] = v.x; l[s] = v.y;
    M = fmaxf(M, m[s]);
  }
  float L = 0.f;
  #pragma unroll
  for (int s=0; s<4; s++){ m[s] = exp2f(m[s] - M); L += l[s]*m[s]; }
  const float inv = 1.0f / L;
  float acc[8] = {0,0,0,0,0,0,0,0};
  #pragma unroll
  for (int s=0; s<4; s++){
    short8 o = *(const short8*)(Opart + (((size_t)qbn*4 + s)*64 + rr)*(size_t)HD + c0);
    float sc = m[s]*inv;
    #pragma unroll
    for (int j=0;j<8;j++) acc[j] += bf2f((u16)o[j]) * sc;
  }
  f32x4 o0 = f32x4{acc[0],acc[1],acc[2],acc[3]};
  f32x4 o1 = f32x4{acc[4],acc[5],acc[6],acc[7]};
  *(f32x4*)(out + (size_t)r*HD + c0)     = o0;
  *(f32x4*)(out + (size_t)r*HD + c0 + 4) = o1;
}

extern "C" void kernel_launch(void* const* d_in, const int* in_sizes, int n_in,
                              void* d_out, int out_size, void* d_ws, size_t ws_size,
                              hipStream_t stream){
  const float* x  = (const float*)d_in[0];
  const float* wq = (const float*)d_in[1];
  const float* wk = (const float*)d_in[2];
  const float* wv = (const float*)d_in[3];
  float* out = (float*)d_out;
  char* ws = (char*)d_ws;

  size_t off = 0;
  u16* wb = (u16*)(ws + off); off += (size_t)3*HD*DMODEL*2;     // 1.5 MB
  float2* tab = (float2*)(ws + off); off += (size_t)SEQ*64*8;   // 2 MB
  u16* qb = (u16*)(ws + off); off += (size_t)BS*HD*2;           // 4 MB
  u16* kb = (u16*)(ws + off); off += (size_t)BS*HD*2;           // 4 MB
  u16* vt = (u16*)(ws + off); off += (size_t)BS*HD*2;           // 4 MB
  u16* Opart = (u16*)(ws + off); off += (size_t)1024*64*HD*2;   // 16.8 MB
  float2* ml = (float2*)(ws + off); off += (size_t)1024*64*8;   // 0.5 MB
  if (ws_size < off) return;  // insufficient workspace -> fail visibly

  hipLaunchKernelGGL(k_prep, dim3(4096),  dim3(256), 0, stream, tab, wq, wk, wv, wb);
  hipLaunchKernelGGL(k_gemm, dim3(1536),  dim3(64),  0, stream, x, wb, tab, qb, kb, vt);
  hipLaunchKernelGGL(k_attn, dim3(1024),  dim3(256), 0, stream, qb, kb, vt, Opart, ml);
  hipLaunchKernelGGL(k_comb, dim3(1024),  dim3(256), 0, stream, Opart, ml, out);
}

// Round 15
// 172.490 us; speedup vs baseline: 1.1671x; 1.1671x over previous
//
#include <hip/hip_runtime.h>
#include <hip/hip_bf16.h>

#define BATCH 4
#define SEQ 4096
#define DMODEL 2048
#define HD 128
#define BS (BATCH*SEQ)

typedef __attribute__((ext_vector_type(8))) short short8;
typedef __attribute__((ext_vector_type(4))) float f32x4;
typedef __attribute__((ext_vector_type(4))) float float4v;
typedef unsigned short u16;
typedef unsigned int u32;

#define LOG2E 1.4426950408889634f
#define SCALE 0.08838834764831845f /* 1/sqrt(128) */

__device__ __forceinline__ u16 f2bf(float f){
  u32 u = __builtin_bit_cast(u32, f);
  u32 r = (u + 0x7FFFu + ((u >> 16) & 1u)) >> 16;
  return (u16)r;
}
__device__ __forceinline__ float bf2f(u16 b){
  u32 u = ((u32)b) << 16;
  return __builtin_bit_cast(float, u);
}

__device__ __forceinline__ void gload16(const void* gptr, void* lptr){
  __builtin_amdgcn_global_load_lds((const __attribute__((address_space(1))) void*)gptr,
                                   (__attribute__((address_space(3))) void*)lptr, 16, 0, 0);
}

// ---------------- trig table + pair-packed weight convert, merged ----------------
// wb rows: [0,64)  Q cols {0-31 lo, 64-95 hi}   [64,128)  Q cols {32-63, 96-127}
//          [128,192) K cols {0-31, 64-95}       [192,256) K cols {32-63, 96-127}
//          [256,320) V cols 0-63                [320,384) V cols 64-127
// (r9-validated packing: each 64-row block is a self-contained RoPE pair-block or V half.)
__global__ __launch_bounds__(256) void k_prep(float2* __restrict__ tab,
                                              const float* __restrict__ wq, const float* __restrict__ wk,
                                              const float* __restrict__ wv, u16* __restrict__ wb){
  int bidx = blockIdx.x;
  if (bidx < 1024){
    int i = bidx*256 + threadIdx.x;            // 4096*64 total
    int s = i >> 6, j = i & 63;
    float invf = (float)pow(10000.0, -(double)j/64.0);
    float ang  = (float)s * invf;              // mimic fp32 reference rounding of the angle
    double a = (double)ang;
    tab[i] = make_float2((float)cos(a), (float)sin(a));
  } else {
    int i = (bidx - 1024)*256 + threadIdx.x;   // 384*2048 total
    int r = i >> 11, k = i & 2047;
    const float* s; int sr;
    if (r < 256){
      s = (r < 128) ? wq : wk;
      int rr = r & 127, blk = rr >> 6, c = rr & 63;
      sr = blk*32 + (c & 31) + ((c >> 5) << 6);
    } else {
      s = wv; sr = r - 256;
    }
    wb[i] = f2bf(s[sr*2048 + k]);
  }
}

// ---------------- fused QKV projection GEMM + RoPE / V^T epilogue ----------------
// BM=32, BN=192 (ng=0: Qb0|Qb1|Kb0 ; ng=1: Kb1|Vlo|Vhi), BK=128 -> 16 K-steps
// (halves the per-step barrier+drain count vs the 75.7us BK=64 kernel).
// 384 threads = 6 waves; wave w owns frag-pair f0=(w>>1)*4+(w&1), f1=f0+2 (lo/hi of one
// pair-block, or two V quarter-columns). LDS 64KB: A bf16 dbuf 2x8K @0, W 48K @16384
// -> 2 blocks/CU. Full vmcnt(0) drains only (no counted-vmcnt race surface).
__global__ __launch_bounds__(384,3) void k_gemm(
    const float* __restrict__ x, const u16* __restrict__ wb, const float2* __restrict__ tab,
    u16* __restrict__ qb, u16* __restrict__ kb, u16* __restrict__ vt)
{
  __shared__ char lds[65536];
  const int tid = threadIdx.x;
  const int ng = blockIdx.x;                   // 0,1 — adjacent blocks share the x-tile
  const int mg = blockIdx.y;                   // 0..511
  const size_t M0 = (size_t)mg * 32;
  const int w = tid >> 6, lane = tid & 63, lr = lane & 15, lg = lane >> 4;
  const int f0 = (w >> 1)*4 + (w & 1), f1 = f0 + 2;

  // W staging: 8 gload16/thread, preswizzled source rows [ng*192, ng*192+192), 256B/row
  int woff[8], wdst[8];
  #pragma unroll
  for (int i=0;i<8;i++){
    int L = i*6144 + tid*16;
    int row = L >> 8, cb = L & 255;
    int scb = cb ^ ((row & 7) << 4);
    woff[i] = (ng*192 + row)*DMODEL + (scb >> 1);
    wdst[i] = 16384 + L;
  }
  // A staging (threads 0..255): 16 fp32 each of the 32x128 tile -> cvt -> 2 ds_write_b128
  const int arow = tid >> 3, ac16 = (tid & 7)*16;
  const float* axp = x + (M0 + arow)*DMODEL + ac16;
  const int asw  = (arow & 7) << 4;
  const int awb0 = arow*256 + ((ac16*2) ^ asw);
  const int awb1 = arow*256 + ((ac16*2 + 16) ^ asw);

  f32x4 acc[2][2];
  #pragma unroll
  for (int i=0;i<2;i++)
    #pragma unroll
    for (int j=0;j<2;j++) acc[i][j] = f32x4{0.f,0.f,0.f,0.f};

  float4v a0, a1, a2, a3;

  // ---- prologue: A(0) regs; W(0) DMA; cvt A(0) -> buf0; drain; barrier ----
  if (tid < 256){
    a0 = *(const float4v*)(axp);     a1 = *(const float4v*)(axp + 4);
    a2 = *(const float4v*)(axp + 8); a3 = *(const float4v*)(axp + 12);
  }
  #pragma unroll
  for (int i=0;i<8;i++) gload16(wb + woff[i], lds + wdst[i]);
  if (tid < 256){
    short8 o;
    o[0]=(short)f2bf(a0[0]); o[1]=(short)f2bf(a0[1]); o[2]=(short)f2bf(a0[2]); o[3]=(short)f2bf(a0[3]);
    o[4]=(short)f2bf(a1[0]); o[5]=(short)f2bf(a1[1]); o[6]=(short)f2bf(a1[2]); o[7]=(short)f2bf(a1[3]);
    *(short8*)(lds + awb0) = o;
    o[0]=(short)f2bf(a2[0]); o[1]=(short)f2bf(a2[1]); o[2]=(short)f2bf(a2[2]); o[3]=(short)f2bf(a2[3]);
    o[4]=(short)f2bf(a3[0]); o[5]=(short)f2bf(a3[1]); o[6]=(short)f2bf(a3[2]); o[7]=(short)f2bf(a3[3]);
    *(short8*)(lds + awb1) = o;
  }
  __builtin_amdgcn_sched_barrier(0);
  asm volatile("s_waitcnt vmcnt(0) lgkmcnt(0)" ::: "memory");
  __builtin_amdgcn_sched_barrier(0);
  __builtin_amdgcn_s_barrier();
  __builtin_amdgcn_sched_barrier(0);

  for (int t=0; t<16; t++){
    const int p = t & 1;
    // [1] issue A(t+1) reg loads early — HBM latency hides under compute + W-wait
    if (t < 15 && tid < 256){
      const float* ap = axp + (t+1)*128;
      a0 = *(const float4v*)(ap);     a1 = *(const float4v*)(ap + 4);
      a2 = *(const float4v*)(ap + 8); a3 = *(const float4v*)(ap + 12);
    }
    // [2] compute step t: Abuf[p] (32x128) x W (192x128), 16 MFMA/wave
    {
      const char* lA = lds + p*8192;
      short8 af[2][4], wf[2][4];
      #pragma unroll
      for (int rf=0; rf<2; rf++)
        #pragma unroll
        for (int ks=0; ks<4; ks++){
          int r = rf*16 + lr;
          af[rf][ks] = *(const short8*)(lA + r*256 + ((ks*64 + lg*16) ^ ((r&7)<<4)));
        }
      #pragma unroll
      for (int nf=0; nf<2; nf++)
        #pragma unroll
        for (int ks=0; ks<4; ks++){
          int r = (nf ? f1 : f0)*16 + lr;
          wf[nf][ks] = *(const short8*)(lds + 16384 + r*256 + ((ks*64 + lg*16) ^ ((r&7)<<4)));
        }
      #pragma unroll
      for (int rf=0; rf<2; rf++)
        #pragma unroll
        for (int nf=0; nf<2; nf++)
          #pragma unroll
          for (int ks=0; ks<4; ks++)
            acc[rf][nf] = __builtin_amdgcn_mfma_f32_16x16x32_bf16(af[rf][ks], wf[nf][ks], acc[rf][nf], 0,0,0);
    }
    if (t < 15){
      // [3] all waves done reading W(t) / Abuf[p]
      __builtin_amdgcn_sched_barrier(0);
      __builtin_amdgcn_s_barrier();
      __builtin_amdgcn_sched_barrier(0);
      // [4] issue W(t+1); cvt+write A(t+1) -> Abuf[p^1]
      const int k0 = (t+1)*128;
      #pragma unroll
      for (int i=0;i<8;i++) gload16(wb + woff[i] + k0, lds + wdst[i]);
      if (tid < 256){
        short8 o;
        o[0]=(short)f2bf(a0[0]); o[1]=(short)f2bf(a0[1]); o[2]=(short)f2bf(a0[2]); o[3]=(short)f2bf(a0[3]);
        o[4]=(short)f2bf(a1[0]); o[5]=(short)f2bf(a1[1]); o[6]=(short)f2bf(a1[2]); o[7]=(short)f2bf(a1[3]);
        *(short8*)(lds + (p^1)*8192 + awb0) = o;
        o[0]=(short)f2bf(a2[0]); o[1]=(short)f2bf(a2[1]); o[2]=(short)f2bf(a2[2]); o[3]=(short)f2bf(a2[3]);
        o[4]=(short)f2bf(a3[0]); o[5]=(short)f2bf(a3[1]); o[6]=(short)f2bf(a3[2]); o[7]=(short)f2bf(a3[3]);
        *(short8*)(lds + (p^1)*8192 + awb1) = o;
      }
      // [5] full drain; next step's reads are safe
      __builtin_amdgcn_sched_barrier(0);
      asm volatile("s_waitcnt vmcnt(0) lgkmcnt(0)" ::: "memory");
      __builtin_amdgcn_sched_barrier(0);
      __builtin_amdgcn_s_barrier();
      __builtin_amdgcn_sched_barrier(0);
    }
  }

  // ---- epilogue: wave-local pair (RoPE) or V columns ----
  const int fr = f0 & 3;          // 0/1: which pair within the sub-block
  const int sb = f0 >> 2;         // sub-block 0..2
  const bool isPair = (ng == 0) || (sb == 0);
  if (isPair){
    u16* dst; int blk;
    if (ng == 0){ if (sb < 2){ dst = qb; blk = sb; } else { dst = kb; blk = 0; } }
    else        { dst = kb; blk = 1; }
    const int j = blk*32 + fr*16 + lr;          // 0..63
    #pragma unroll
    for (int rf=0; rf<2; rf++)
      #pragma unroll
      for (int reg=0; reg<4; reg++){
        size_t grow = M0 + rf*16 + lg*4 + reg;
        int spos = (int)(grow & (SEQ-1));
        float2 cs = tab[spos*64 + j];
        float lo = acc[rf][0][reg];
        float hi = acc[rf][1][reg];
        dst[grow*HD + j]      = f2bf(lo*cs.x - hi*cs.y);
        dst[grow*HD + j + 64] = f2bf(hi*cs.x + lo*cs.y);
      }
  } else {
    const int c0 = f0*16 + lr - 64;             // V cols: f0 in {4,5,8,9}
    #pragma unroll
    for (int rf=0; rf<2; rf++)
      #pragma unroll
      for (int reg=0; reg<4; reg++){
        size_t grow = M0 + rf*16 + lg*4 + reg;
        size_t b = grow >> 12;
        size_t spos = grow & (SEQ-1);
        vt[(b*HD + c0)*SEQ + spos]      = f2bf(acc[rf][0][reg]);
        vt[(b*HD + c0 + 32)*SEQ + spos] = f2bf(acc[rf][1][reg]);
      }
  }
}

// ---------------- causal flash attention, 4-way KV split (flash-decoding) ----------------
// grid 1024: (batch, 64-row q-tile, kv-split). 4 waves x 16 q-rows share staged lK/lV.
// LDS 40KB -> 4 blocks/CU -> 16 waves/CU. Partials (O bf16, ml fp32) to workspace.
__global__ __launch_bounds__(256) void k_attn(
    const u16* __restrict__ qbuf, const u16* __restrict__ kb, const u16* __restrict__ vt,
    u16* __restrict__ Opart, float2* __restrict__ ml)
{
  __shared__ u16 lK[64*128];    // byte = kv*256 + (cb ^ ((kv&7)<<4))
  __shared__ u16 lV[128*64];    // byte = d*128  + (cb ^ ((d&7)<<4))
  __shared__ u16 lP[4][16*64];  // per-wave, byte = r*128 + (cb ^ ((r&7)<<4))
  const int tid = threadIdx.x;
  const int bid = blockIdx.x;
  const int x = bid & 7, idx = bid >> 3;
  const int b = x >> 1, half = x & 1;
  const int qt = 63 - (idx >> 1);              // heavy tiles first
  const int sp = (idx & 1) + 2*half;           // kv-split 0..3
  const int qbn = b*64 + qt;                   // 0..255
  const int w = tid >> 6, lane = tid & 63, lr = lane & 15, lg = lane >> 4;

  // balanced contiguous partition of tiles [0, qt] into 4 chunks
  const int n = qt + 1, cbase = n >> 2, crem = n & 3;
  const int cnt = cbase + (sp < crem ? 1 : 0);
  const int klo = sp*cbase + (sp < crem ? sp : crem);
  const int khi = klo + cnt;
  const size_t prow0 = ((size_t)qbn*4 + sp)*64;

  if (cnt == 0){                               // empty split: mark and exit (block-uniform)
    if (lr == 0){
      #pragma unroll
      for (int reg=0; reg<4; reg++)
        ml[prow0 + w*16 + lg*4 + reg] = make_float2(-1e30f, 0.f);
    }
    return;
  }

  const size_t qrow = (size_t)b*SEQ + qt*64 + w*16 + lr;
  short8 aq[4];
  #pragma unroll
  for (int ks=0; ks<4; ks++)
    aq[ks] = *(const short8*)(qbuf + qrow*HD + ks*32 + lg*8);

  f32x4 accO[8];
  #pragma unroll
  for (int i=0;i<8;i++) accO[i] = f32x4{0.f,0.f,0.f,0.f};
  float m2[4]   = {-1e30f,-1e30f,-1e30f,-1e30f};
  float lsum[4] = {0.f,0.f,0.f,0.f};

  const int Lb = tid*16;
  const float cfac = SCALE * LOG2E;

  for (int kt = klo; kt < khi; kt++){
    #pragma unroll
    for (int i=0;i<4;i++){
      int L = i*4096 + Lb;
      { int row = L >> 8, cb = L & 255;
        int scb = cb ^ ((row & 7) << 4);
        gload16(kb + ((size_t)b*SEQ + kt*64 + row)*HD + (scb>>1), ((char*)lK) + L); }
      { int row = L >> 7, cb = L & 127;
        int scb = cb ^ ((row & 7) << 4);
        gload16(vt + ((size_t)b*HD + row)*SEQ + kt*64 + (scb>>1), ((char*)lV) + L); }
    }
    __syncthreads();

    // S = Q K^T  (16 q-rows x 64 kv) in log2-domain units
    f32x4 sc[4];
    #pragma unroll
    for (int nf=0; nf<4; nf++){
      sc[nf] = f32x4{0.f,0.f,0.f,0.f};
      #pragma unroll
      for (int ks=0; ks<4; ks++){
        int r = nf*16 + lr;
        int byte = r*256 + ((ks*64 + lg*16) ^ ((r&7)<<4));
        short8 bk = *(const short8*)((const char*)lK + byte);
        sc[nf] = __builtin_amdgcn_mfma_f32_16x16x32_bf16(aq[ks], bk, sc[nf], 0,0,0);
      }
      sc[nf] *= cfac;
    }
    if (kt == qt){                            // diagonal tile: causal mask
      #pragma unroll
      for (int nf=0; nf<4; nf++)
        #pragma unroll
        for (int reg=0; reg<4; reg++){
          int col = nf*16 + lr;
          int row = w*16 + lg*4 + reg;
          if (col > row) sc[nf][reg] = -1e30f;
        }
    }
    float al[4];
    #pragma unroll
    for (int reg=0; reg<4; reg++){
      float v = fmaxf(fmaxf(sc[0][reg], sc[1][reg]), fmaxf(sc[2][reg], sc[3][reg]));
      v = fmaxf(v, __shfl_xor(v, 1));
      v = fmaxf(v, __shfl_xor(v, 2));
      v = fmaxf(v, __shfl_xor(v, 4));
      v = fmaxf(v, __shfl_xor(v, 8));
      float mnew = fmaxf(m2[reg], v);
      al[reg] = exp2f(m2[reg] - mnew);
      m2[reg] = mnew;
    }
    float prs[4] = {0.f,0.f,0.f,0.f};
    #pragma unroll
    for (int nf=0; nf<4; nf++)
      #pragma unroll
      for (int reg=0; reg<4; reg++){
        float p = exp2f(sc[nf][reg] - m2[reg]);
        prs[reg] += p;
        int r = lg*4 + reg;
        int byte = r*128 + ((nf*32 + lr*2) ^ ((r&7)<<4));
        *(u16*)(((char*)lP[w]) + byte) = f2bf(p);
      }
    f32x4 alv = f32x4{al[0], al[1], al[2], al[3]};
    #pragma unroll
    for (int reg=0; reg<4; reg++){
      float v = prs[reg];
      v += __shfl_xor(v, 1);
      v += __shfl_xor(v, 2);
      v += __shfl_xor(v, 4);
      v += __shfl_xor(v, 8);
      lsum[reg] = lsum[reg]*al[reg] + v;
    }
    #pragma unroll
    for (int cf=0; cf<8; cf++) accO[cf] *= alv;

    short8 pa[2];
    #pragma unroll
    for (int ks=0; ks<2; ks++){
      int byte = lr*128 + ((ks*64 + lg*16) ^ ((lr&7)<<4));
      pa[ks] = *(const short8*)(((const char*)lP[w]) + byte);
    }
    #pragma unroll
    for (int cf=0; cf<8; cf++){
      #pragma unroll
      for (int ks=0; ks<2; ks++){
        int d = cf*16 + lr;
        int byte = d*128 + ((ks*64 + lg*16) ^ ((d&7)<<4));
        short8 bv = *(const short8*)(((const char*)lV) + byte);
        accO[cf] = __builtin_amdgcn_mfma_f32_16x16x32_bf16(pa[ks], bv, accO[cf], 0,0,0);
      }
    }
    __syncthreads();
  }

  // partial epilogue: bf16 accO + (m, l) per row
  #pragma unroll
  for (int reg=0; reg<4; reg++){
    size_t pr = prow0 + w*16 + lg*4 + reg;
    #pragma unroll
    for (int cf=0; cf<8; cf++)
      Opart[pr*HD + cf*16 + lr] = f2bf(accO[cf][reg]);
  }
  if (lr == 0){
    #pragma unroll
    for (int reg=0; reg<4; reg++)
      ml[prow0 + w*16 + lg*4 + reg] = make_float2(m2[reg], lsum[reg]);
  }
}

// ---------------- combine partials: out = sum_s O_s * 2^(m_s-M) / L ----------------
// grid 1024: 16 rows/block, 8 cols/thread (bf16 Opart short8 reads).
__global__ __launch_bounds__(256) void k_comb(
    const u16* __restrict__ Opart, const float2* __restrict__ ml, float* __restrict__ out)
{
  const int t = threadIdx.x;
  const int r = blockIdx.x*16 + (t >> 4);      // global row 0..16383
  const int c0 = (t & 15)*8;
  const int qbn = r >> 6, rr = r & 63;
  float m[4], l[4], M = -1e30f;
  #pragma unroll
  for (int s=0; s<4; s++){
    float2 v = ml[((size_t)qbn*4 + s)*64 + rr];
    m[s] = v.x; l[s] = v.y;
    M = fmaxf(M, m[s]);
  }
  float L = 0.f;
  #pragma unroll
  for (int s=0; s<4; s++){ m[s] = exp2f(m[s] - M); L += l[s]*m[s]; }
  const float inv = 1.0f / L;
  float acc[8] = {0,0,0,0,0,0,0,0};
  #pragma unroll
  for (int s=0; s<4; s++){
    short8 o = *(const short8*)(Opart + (((size_t)qbn*4 + s)*64 + rr)*(size_t)HD + c0);
    float sc = m[s]*inv;
    #pragma unroll
    for (int j=0;j<8;j++) acc[j] += bf2f((u16)o[j]) * sc;
  }
  f32x4 o0 = f32x4{acc[0],acc[1],acc[2],acc[3]};
  f32x4 o1 = f32x4{acc[4],acc[5],acc[6],acc[7]};
  *(f32x4*)(out + (size_t)r*HD + c0)     = o0;
  *(f32x4*)(out + (size_t)r*HD + c0 + 4) = o1;
}

extern "C" void kernel_launch(void* const* d_in, const int* in_sizes, int n_in,
                              void* d_out, int out_size, void* d_ws, size_t ws_size,
                              hipStream_t stream){
  const float* x  = (const float*)d_in[0];
  const float* wq = (const float*)d_in[1];
  const float* wk = (const float*)d_in[2];
  const float* wv = (const float*)d_in[3];
  float* out = (float*)d_out;
  char* ws = (char*)d_ws;

  size_t off = 0;
  u16* wb = (u16*)(ws + off); off += (size_t)3*HD*DMODEL*2;     // 1.5 MB
  float2* tab = (float2*)(ws + off); off += (size_t)SEQ*64*8;   // 2 MB
  u16* qb = (u16*)(ws + off); off += (size_t)BS*HD*2;           // 4 MB
  u16* kb = (u16*)(ws + off); off += (size_t)BS*HD*2;           // 4 MB
  u16* vt = (u16*)(ws + off); off += (size_t)BS*HD*2;           // 4 MB
  u16* Opart = (u16*)(ws + off); off += (size_t)1024*64*HD*2;   // 16.8 MB
  float2* ml = (float2*)(ws + off); off += (size_t)1024*64*8;   // 0.5 MB
  if (ws_size < off) return;  // insufficient workspace -> fail visibly

  hipLaunchKernelGGL(k_prep, dim3(4096),   dim3(256), 0, stream, tab, wq, wk, wv, wb);
  hipLaunchKernelGGL(k_gemm, dim3(2,512),  dim3(384), 0, stream, x, wb, tab, qb, kb, vt);
  hipLaunchKernelGGL(k_attn, dim3(1024),   dim3(256), 0, stream, qb, kb, vt, Opart, ml);
  hipLaunchKernelGGL(k_comb, dim3(1024),   dim3(256), 0, stream, Opart, ml, out);
}